// Round 18
// baseline (337.078 us; speedup 1.0000x reference)
//
#include <hip/hip_runtime.h>

#define N_PTS 4096
#define NB    8
#define KNN   20
#define FIN   67
#define COUT  64
#define SEG   8
#define SEGN  (N_PTS / SEG)   // 512 candidates per segment-wave
#define SLOTS 16              // LDS stack slots per thread
#define BT    512             // knn block threads (8 waves)

typedef unsigned short u16;
typedef unsigned int   u32;
typedef unsigned long long u64;

// ws layout (bytes)
#define KNN_BYTES 1310720u                      // 8*4096*20*2
#define FT_OFF    1310720u                      // ft[b][n][64] f32 = 8388608
#define PK_OFF    (FT_OFF + 8388608u)           // pack[b][n] float4 = 524288
#define WS_NEED   (PK_OFF + 524288u)            // 10223616

__device__ __forceinline__ float finf() { return __uint_as_float(0x7f800000u); }

// Order-preserving f32 -> u32 map (total order, matches IEEE < on non-NaN).
__device__ __forceinline__ u32 fmap(float f) {
    u32 b = __float_as_uint(f);
    return b ^ ((u32)((int)b >> 31) | 0x80000000u);
}

// sq = (x*x + y*y) + z*z, all f32, no FMA (matches np op order).
__device__ __forceinline__ float sq_exact(float x, float y, float z) {
#pragma clang fp contract(off)
    float s = (x * x + y * y) + z * z;
    return s;
}

// dist = (sq_i - 2*dot) + sq_j, dot = (x_i*x_j + y_i*y_j) + z_i*z_j, no FMA.
__device__ __forceinline__ float dist_from_sq(float xi, float yi, float zi, float sqi,
                                              float xj, float yj, float zj, float sqj) {
#pragma clang fp contract(off)
    float d0 = xi * xj, d1 = yi * yj, d2 = zi * zj;
    float dot = (d0 + d1) + d2;
    float d = (sqi - 2.0f * dot) + sqj;
    return d;
}

__device__ __forceinline__ float dist_exact(float xi, float yi, float zi, float sqi,
                                            float xj, float yj, float zj) {
#pragma clang fp contract(off)
    float d0 = xi * xj, d1 = yi * yj, d2 = zi * zj;
    float dot = (d0 + d1) + d2;
    float sqj = (xj * xj + yj * yj) + zj * zj;
    float d = (sqi - 2.0f * dot) + sqj;
    return d;
}

// u64 key = fmap(d) << 12 | j  — plain u64 < is EXACT (d, j) lex order.
__device__ __forceinline__ void cswap64(u64& a, u64& b) {
    bool sw = b < a;
    u64 na = sw ? b : a, nb = sw ? a : b;
    a = na; b = nb;
}

// ---------------- Kernel 0: transpose/pack + out0 passthrough ----------------
__global__ __launch_bounds__(256) void transpose_kernel(
    const float* __restrict__ xloc, const float* __restrict__ xfeat,
    float* __restrict__ ft, float4* __restrict__ pack, float* __restrict__ out) {
    __shared__ float tile[64][65];
    const int tid = threadIdx.x;
    const int blk = blockIdx.x;               // b*64 + ntile
    const int b   = blk >> 6;
    const int n0  = (blk & 63) << 6;
    const int tx  = tid & 63, w = tid >> 6;

    if (tid < 48) {
        int idx4 = blk * 48 + tid;            // 512*48 float4 = 98304 f32
        ((float4*)out)[idx4] = ((const float4*)xloc)[idx4];
    }
    if (w == 0) {
        float x = xloc[((size_t)b * 3 + 0) * N_PTS + n0 + tx];
        float y = xloc[((size_t)b * 3 + 1) * N_PTS + n0 + tx];
        float z = xloc[((size_t)b * 3 + 2) * N_PTS + n0 + tx];
        pack[((size_t)b << 12) + n0 + tx] = make_float4(x, y, z, sq_exact(x, y, z));
    }
#pragma unroll
    for (int k = 0; k < 16; ++k) {
        int c = w * 16 + k;
        tile[tx][c] = xfeat[((size_t)(b << 6) + c) * N_PTS + n0 + tx];
    }
    __syncthreads();
#pragma unroll
    for (int k = 0; k < 16; ++k) {
        int n = w * 16 + k;
        ft[(((size_t)(b << 12)) + n0 + n) * 64 + tx] = tile[n][tx];
    }
}

// ---------------- Kernel 1: kNN v4 — cross-segment shared threshold ----------
// Block = 512 threads = 8 waves; wave w = segment w (512 candidates), lane =
// query (64/block). All 8 segment-waves serve the SAME 64 queries, so they
// SHARE a per-query threshold thrS[64] in LDS (volatile; raced read-min-write
// is monotone-conservative: any stale/lost update only loosens the gate).
// Gate: d <= thr. Exactness: rejected => d > v where v = some segment's
// 21st-smallest-so-far => >=21 candidates (>=20 non-self) strictly better =>
// non-self global rank >= 21 => cannot be in the final top-20. Self (d=+0.0)
// flows through and is compacted out of the exact top-21 at publish.
__global__ __launch_bounds__(BT) void knn_v4_kernel(
    const float4* __restrict__ pack, u16* __restrict__ knn_out) {
    __shared__ u64 stk[SLOTS][BT];            // 64 KB, bank-free SoA
    __shared__ u64 ext[KNN - SLOTS][BT];      // 16 KB (publish slots 16..19)
    __shared__ float thrS[64];                // shared per-query threshold
    const int tid  = threadIdx.x;
    const int lane = tid & 63;                // query within tile
    const int blk  = blockIdx.x;              // b*64 + qtile
    const int b    = blk >> 6;
    const int tile = blk & 63;
    const int i    = (tile << 6) | lane;
    const float4* pb = pack + ((size_t)b << 12);

    volatile float* vthr = thrS;
    if (tid < 64) thrS[tid] = finf();

    // Wave-uniform segment base -> scalar loads in the hot loop.
    const int segu  = __builtin_amdgcn_readfirstlane(tid >> 6);
    const float4* base = pb + segu * SEGN;

    const float4 qp = pb[i];
    const float xi = qp.x, yi = qp.y, zi = qp.z, sqi = qp.w;

    __syncthreads();                          // thrS initialized

    u64 ld[32];
#pragma unroll
    for (int t = 0; t < 32; ++t) ld[t] = ~0ull;
    float thr = finf();
    int cnt = 0;

    auto merge_stack = [&]() {
        u64 bd[SLOTS];
#pragma unroll
        for (int t = 0; t < SLOTS; ++t) bd[t] = (t < cnt) ? stk[t][tid] : ~0ull;
#pragma unroll
        for (int k = 2; k <= SLOTS; k <<= 1) {
#pragma unroll
            for (int s = k >> 1; s > 0; s >>= 1) {
#pragma unroll
                for (int t = 0; t < SLOTS; ++t) {
                    int l = t ^ s;
                    if (l > t) {
                        if ((t & k) == 0) cswap64(bd[t], bd[l]);
                        else              cswap64(bd[l], bd[t]);
                    }
                }
            }
        }
#pragma unroll
        for (int t = 0; t < SLOTS; ++t) cswap64(ld[31 - t], bd[t]);
#pragma unroll
        for (int k = 16; k >= 1; k >>= 1) {
#pragma unroll
            for (int t = 0; t < 32; ++t) {
                if ((t & k) == 0) cswap64(ld[t], ld[t | k]);
            }
        }
        // own 21st-best distance (ld[KNN]); guard padding (all-ones).
        u32 m = (u32)(ld[KNN] >> 12);
        u32 db = m ^ ((m & 0x80000000u) ? 0x80000000u : 0xFFFFFFFFu);
        float own = (m == 0xFFFFFFFFu) ? finf() : __uint_as_float(db);
        // Fold into the shared per-query threshold (racy but monotone-safe).
        float sh = vthr[lane];
        float nw = fminf(own, sh);
        vthr[lane] = nw;
        thr = nw;
        cnt = 0;
    };

    const int jbase = segu * SEGN;
    for (int c = 0; c < SEGN; c += 4) {
        // Refresh gate from the shared threshold (other segments tighten it).
        thr = fminf(thr, vthr[lane]);
        float4 p0 = base[c + 0], p1 = base[c + 1];
        float4 p2 = base[c + 2], p3 = base[c + 3];
#pragma unroll
        for (int qq = 0; qq < 4; ++qq) {
            float4 pk = (qq == 0) ? p0 : (qq == 1) ? p1 : (qq == 2) ? p2 : p3;
            float d = dist_from_sq(xi, yi, zi, sqi, pk.x, pk.y, pk.z, pk.w);
            // Gate d <= thr (equality ACCEPTED — required for cross-segment
            // sharing; see kernel comment for the exactness proof).
            if (d <= thr) {
                u64 key = ((u64)fmap(d) << 12) | (u32)(jbase + c + qq);
                stk[cnt][tid] = key;
                ++cnt;
            }
        }
        // Entering a chunk all lanes have cnt <= 12; +4 max => <= 16. ✓
        if (__any(cnt >= SLOTS - 3)) merge_stack();
    }
    merge_stack();                            // drain

    // Publish exact top-20 EXCLUDING self: compact ld[0..20] (exact top-21).
    u64 pub[KNN];
    {
        bool sf = false;
#pragma unroll
        for (int t = 0; t < KNN + 1; ++t) {
            bool isself = ((u32)(ld[t] & 0xFFFull) == (u32)i);
            sf = sf || isself;
            if (t < KNN) pub[t] = sf ? ld[t + 1] : ld[t];
        }
    }
#pragma unroll
    for (int t = 0; t < SLOTS; ++t) stk[t][tid] = pub[t];
#pragma unroll
    for (int t = SLOTS; t < KNN; ++t) ext[t - SLOTS][tid] = pub[t];
    __syncthreads();

    // Exact 8-way tournament merge per query (threads 0..63).
    if (tid < 64) {
        const int q = tid;
        const int row = (b << 12) | (tile << 6) | q;
        int pp[SEG];
        u64 kk[SEG];
#pragma unroll
        for (int s = 0; s < SEG; ++s) { pp[s] = 0; kk[s] = stk[0][q + 64 * s]; }
#pragma unroll
        for (int t = 0; t < KNN; ++t) {
            u64 best = kk[0]; int sm = 0;
#pragma unroll
            for (int s = 1; s < SEG; ++s)
                if (kk[s] < best) { best = kk[s]; sm = s; }
            knn_out[(size_t)row * KNN + t] = (u16)(best & 0xFFFull);
#pragma unroll
            for (int s = 0; s < SEG; ++s) {
                if (s == sm) {
                    int p = ++pp[s];
                    int col = q + 64 * s;
                    kk[s] = (p < KNN) ? ((p < SLOTS) ? stk[p][col] : ext[p - SLOTS][col])
                                      : ~0ull;
                }
            }
        }
    }
}

// ---------------- Kernel 2: conv — 16-pt tiles, LDS index preload ----------------
__global__ __launch_bounds__(128) void conv_g2_kernel(
    const float* __restrict__ Wrel,
    const float* __restrict__ brel,
    const float* __restrict__ Wroot,
    const u16* __restrict__ knn_in,
    const float* __restrict__ ft,
    const float4* __restrict__ pack,
    float* __restrict__ out) {
    __shared__ float aggf[16][69];
    __shared__ float hif[16][69];
    __shared__ u16 idx[16 * KNN];             // 640 B
    const int tid = threadIdx.x;
    const int blk = blockIdx.x;               // b*256 + tile
    const int b   = blk >> 8;
    const int i0  = (blk & 255) << 4;
    const int lane = tid & 63, w = tid >> 6;
    const float* ftb = ft + (((size_t)b << 12)) * 64;
    const float* pkb = (const float*)(pack + ((size_t)b << 12));

    {
        const u32* src = (const u32*)(knn_in + (size_t)((b << 12) | i0) * KNN);
        for (int k = tid; k < 16 * KNN / 2; k += 128) ((u32*)idx)[k] = src[k];
    }
    __syncthreads();

#pragma unroll
    for (int pp = 0; pp < 8; ++pp) {
        int p = w * 8 + pp;
        int i = i0 + p;
        float af = 0.f, al = 0.f;
        float hfv = ftb[(size_t)i * 64 + lane];
        float hlv = (lane < 3) ? pkb[(size_t)i * 4 + lane] : 0.f;
#pragma unroll
        for (int t = 0; t < KNN; ++t) {       // ascending (dist, idx) order
            int j = idx[p * KNN + t];
            af += ftb[(size_t)j * 64 + lane];
            if (lane < 3) al += pkb[(size_t)j * 4 + lane];
        }
        aggf[p][3 + lane] = af;
        hif[p][3 + lane]  = hfv;
        if (lane < 3) { aggf[p][lane] = al; hif[p][lane] = hlv; }
    }
    __syncthreads();

    const int p2 = tid & 15, oct = tid >> 4;  // 8 channels per thread
    const int i2 = i0 + p2;
    float rel[8], root[8];
#pragma unroll
    for (int c = 0; c < 8; ++c) { rel[c] = 0.f; root[c] = 0.f; }
    for (int f = 0; f < FIN; ++f) {
        float a = aggf[p2][f];
        float h = hif[p2][f];
        const float4* w4r = (const float4*)(Wrel + f * COUT + oct * 8);
        const float4* w4o = (const float4*)(Wroot + f * COUT + oct * 8);
#pragma unroll
        for (int c4 = 0; c4 < 2; ++c4) {
            float4 wr = w4r[c4], wo = w4o[c4];
            rel[c4 * 4 + 0] += a * wr.x;  root[c4 * 4 + 0] += h * wo.x;
            rel[c4 * 4 + 1] += a * wr.y;  root[c4 * 4 + 1] += h * wo.y;
            rel[c4 * 4 + 2] += a * wr.z;  root[c4 * 4 + 2] += h * wo.z;
            rel[c4 * 4 + 3] += a * wr.w;  root[c4 * 4 + 3] += h * wo.w;
        }
    }
    const size_t ob = (size_t)NB * 3 * N_PTS + (size_t)b * COUT * N_PTS;
#pragma unroll
    for (int c = 0; c < 8; ++c) {
        int cc = oct * 8 + c;
        float acc = (rel[c] + brel[cc]) + root[c];  // einsum + b_rel + einsum order
        out[ob + (size_t)cc * N_PTS + i2] = fmaxf(acc, 0.f);
    }
}

// ================= r14 fallback path (proven, 379us) =================
__global__ __launch_bounds__(256) void knn_seg8_kernel(
    const float* __restrict__ xloc, u16* __restrict__ knn_out) {
    __shared__ u64 stk[SLOTS][256];
    __shared__ u64 ext[KNN - SLOTS][256];
    const int tid  = threadIdx.x;
    const int q    = tid & 31;
    const int seg  = tid >> 5;
    const int blk  = blockIdx.x;
    const int b    = blk >> 7;
    const int i    = ((blk & 127) << 5) | q;
    const float* xb = xloc + (size_t)b * 3 * N_PTS;

    const float xi = xb[i], yi = xb[N_PTS + i], zi = xb[2 * N_PTS + i];
    const float sqi = sq_exact(xi, yi, zi);

    u64 ld[32];
#pragma unroll
    for (int t = 0; t < 32; ++t) ld[t] = ~0ull;
    u64 thr = ~0ull;
    int cnt = 0;

    auto merge_stack = [&]() {
        u64 bd[SLOTS];
#pragma unroll
        for (int t = 0; t < SLOTS; ++t) bd[t] = (t < cnt) ? stk[t][tid] : ~0ull;
#pragma unroll
        for (int k = 2; k <= SLOTS; k <<= 1) {
#pragma unroll
            for (int s = k >> 1; s > 0; s >>= 1) {
#pragma unroll
                for (int t = 0; t < SLOTS; ++t) {
                    int l = t ^ s;
                    if (l > t) {
                        if ((t & k) == 0) cswap64(bd[t], bd[l]);
                        else              cswap64(bd[l], bd[t]);
                    }
                }
            }
        }
#pragma unroll
        for (int t = 0; t < SLOTS; ++t) cswap64(ld[31 - t], bd[t]);
#pragma unroll
        for (int k = 16; k >= 1; k >>= 1) {
#pragma unroll
            for (int t = 0; t < 32; ++t) {
                if ((t & k) == 0) cswap64(ld[t], ld[t | k]);
            }
        }
        thr = ld[KNN - 1];
        cnt = 0;
    };

    const int cbase = seg * 512;
    for (int c = 0; c < 512; c += 4) {
        const int cc = cbase + c;
        float4 fx = *(const float4*)(xb + cc);
        float4 fy = *(const float4*)(xb + N_PTS + cc);
        float4 fz = *(const float4*)(xb + 2 * N_PTS + cc);
#pragma unroll
        for (int qq = 0; qq < 4; ++qq) {
            float xj = (qq == 0) ? fx.x : (qq == 1) ? fx.y : (qq == 2) ? fx.z : fx.w;
            float yj = (qq == 0) ? fy.x : (qq == 1) ? fy.y : (qq == 2) ? fy.z : fy.w;
            float zj = (qq == 0) ? fz.x : (qq == 1) ? fz.y : (qq == 2) ? fz.z : fz.w;
            float sqj = sq_exact(xj, yj, zj);
            float d = dist_from_sq(xi, yi, zi, sqi, xj, yj, zj, sqj);
            int j = cc + qq;
            u64 key = ((u64)fmap(d) << 12) | (u32)j;
            bool ok = (j != i) && (key < thr);
            if (ok) { stk[cnt][tid] = key; ++cnt; }
        }
        if (__any(cnt >= SLOTS - 3)) merge_stack();
    }
    merge_stack();

#pragma unroll
    for (int t = 0; t < SLOTS; ++t) stk[t][tid] = ld[t];
#pragma unroll
    for (int t = SLOTS; t < KNN; ++t) ext[t - SLOTS][tid] = ld[t];
    __syncthreads();

    if (tid < 32) {
        const int col0 = tid;
        const int row  = (b << 12) | ((blk & 127) << 5) | tid;
        int  pp[8];
        u64  kk[8];
#pragma unroll
        for (int s = 0; s < 8; ++s) { pp[s] = 0; kk[s] = stk[0][col0 + 32 * s]; }
#pragma unroll
        for (int t = 0; t < KNN; ++t) {
            u64 best = kk[0]; int sm = 0;
#pragma unroll
            for (int s = 1; s < 8; ++s)
                if (kk[s] < best) { best = kk[s]; sm = s; }
            knn_out[(size_t)row * KNN + t] = (u16)(best & 0xFFFu);
#pragma unroll
            for (int s = 0; s < 8; ++s) {
                if (s == sm) {
                    int p = ++pp[s];
                    int col = col0 + 32 * s;
                    kk[s] = (p < KNN) ? ((p < SLOTS) ? stk[p][col] : ext[p - SLOTS][col])
                                      : ~0ull;
                }
            }
        }
    }
}

__global__ __launch_bounds__(128) void conv_q_kernel(
    const float* __restrict__ xloc,
    const float* __restrict__ xfeat,
    const float* __restrict__ Wrel,
    const float* __restrict__ brel,
    const float* __restrict__ Wroot,
    const u16* __restrict__ knn_in,
    float* __restrict__ out) {
    __shared__ float rowbuf[2][N_PTS];
    const int tid = threadIdx.x;
    const int p   = tid & 31;
    const int qtr = tid >> 5;
    const int blk = blockIdx.x;
    const int b   = blk >> 7;
    const int i   = ((blk & 127) << 5) | p;
    const float* xb = xloc + (size_t)b * 3 * N_PTS;
    const float* fb = xfeat + (size_t)b * 64 * N_PTS;

    if (qtr == 0) {
#pragma unroll
        for (int c = 0; c < 3; ++c)
            out[((size_t)b * 3 + c) * N_PTS + i] = xb[(size_t)c * N_PTS + i];
    }

    u32 kl[KNN / 2];
    const u32* kp = (const u32*)(knn_in + (size_t)((b << 12) | i) * KNN);
#pragma unroll
    for (int w = 0; w < KNN / 2; ++w) kl[w] = kp[w];
    int jj[KNN];
#pragma unroll
    for (int t = 0; t < KNN; ++t) jj[t] = (int)((kl[t >> 1] >> ((t & 1) * 16)) & 0xFFFFu);

    float rel[16], root[16];
#pragma unroll
    for (int c = 0; c < 16; ++c) { rel[c] = 0.f; root[c] = 0.f; }

    auto stage = [&](int f) {
        const float* src = (f < 3) ? (xb + (size_t)f * N_PTS)
                                   : (fb + (size_t)(f - 3) * N_PTS);
        const float4* s4 = (const float4*)src;
        float4* d4 = (float4*)rowbuf[f & 1];
#pragma unroll
        for (int w = 0; w < 8; ++w) {
            int idxw = w * 128 + tid;
            d4[idxw] = s4[idxw];
        }
    };

    stage(0);
    __syncthreads();

    for (int f = 0; f < FIN; ++f) {
        if (f + 1 < FIN) stage(f + 1);
        const float* cur = rowbuf[f & 1];
        float hf = cur[i];
        float af = 0.f;
#pragma unroll
        for (int t = 0; t < KNN; ++t) af += cur[jj[t]];

        const float4* w4r = (const float4*)(Wrel + f * COUT + qtr * 16);
        const float4* w4o = (const float4*)(Wroot + f * COUT + qtr * 16);
#pragma unroll
        for (int c4 = 0; c4 < 4; ++c4) {
            float4 wr = w4r[c4], wo = w4o[c4];
            rel[c4 * 4 + 0] += af * wr.x;  root[c4 * 4 + 0] += hf * wo.x;
            rel[c4 * 4 + 1] += af * wr.y;  root[c4 * 4 + 1] += hf * wo.y;
            rel[c4 * 4 + 2] += af * wr.z;  root[c4 * 4 + 2] += hf * wo.z;
            rel[c4 * 4 + 3] += af * wr.w;  root[c4 * 4 + 3] += hf * wo.w;
        }
        __syncthreads();
    }

    const size_t ob = (size_t)NB * 3 * N_PTS + (size_t)b * COUT * N_PTS;
#pragma unroll
    for (int c = 0; c < 16; ++c) {
        int cc = qtr * 16 + c;
        float acc = (rel[c] + brel[cc]) + root[c];
        out[ob + (size_t)cc * N_PTS + i] = fmaxf(acc, 0.f);
    }
}

// ---------------- Last-resort fallback: proven round-7 monolith ----------------
__device__ __forceinline__ void insert3(float d, int c,
                                        float& v0, float& v1, float& v2,
                                        int& c0, int& c1, int& c2) {
    if (d < v2) {
        if (d < v1) {
            if (d < v0) { v2 = v1; c2 = c1; v1 = v0; c1 = c0; v0 = d; c0 = c; }
            else        { v2 = v1; c2 = c1; v1 = d;  c1 = c; }
        } else          { v2 = d;  c2 = c; }
    }
}

__global__ __launch_bounds__(64) void pcd_all(
    const float* __restrict__ xloc,
    const float* __restrict__ xfeat,
    const float* __restrict__ Wrel,
    const float* __restrict__ brel,
    const float* __restrict__ Wroot,
    float* __restrict__ out) {
    const int lane = threadIdx.x;
    const int row  = blockIdx.x;
    const int b    = row >> 12;
    const int i    = row & (N_PTS - 1);
    const float* xb = xloc + (size_t)b * 3 * N_PTS;

    if (lane < 3) {
        out[((size_t)b * 3 + lane) * N_PTS + i] = xb[(size_t)lane * N_PTS + i];
    }

    const float xi  = xb[i];
    const float yi  = xb[N_PTS + i];
    const float zi  = xb[2 * N_PTS + i];
    const float sqi = sq_exact(xi, yi, zi);

    float v0 = 1e30f, v1 = 1e30f, v2 = 1e30f;
    int   c0 = -1,    c1 = -1,    c2 = -1;

    for (int s = 0; s < 16; ++s) {
        int jb = s * 256 + lane * 4;
        float4 fx = *(const float4*)(xb + jb);
        float4 fy = *(const float4*)(xb + N_PTS + jb);
        float4 fz = *(const float4*)(xb + 2 * N_PTS + jb);
#pragma unroll
        for (int q = 0; q < 4; ++q) {
            float xj = (q == 0) ? fx.x : (q == 1) ? fx.y : (q == 2) ? fx.z : fx.w;
            float yj = (q == 0) ? fy.x : (q == 1) ? fy.y : (q == 2) ? fy.z : fy.w;
            float zj = (q == 0) ? fz.x : (q == 1) ? fz.y : (q == 2) ? fz.z : fz.w;
            int j = jb + q;
            float d = (j == i) ? 1e30f : dist_exact(xi, yi, zi, sqi, xj, yj, zj);
            insert3(d, s * 4 + q, v0, v1, v2, c0, c1, c2);
        }
    }

    u64 taken = 0;
    __shared__ int knn[KNN];

    for (int t = 0; t < KNN; ++t) {
        float bv = v0;
        int   bj = (c0 >= 0) ? (((c0 >> 2) << 8) + lane * 4 + (c0 & 3)) : (N_PTS - 1);
#pragma unroll
        for (int m = 1; m < 64; m <<= 1) {
            float ov = __shfl_xor(bv, m);
            int   oj = __shfl_xor(bj, m);
            if (ov < bv || (ov == bv && oj < bj)) { bv = ov; bj = oj; }
        }
        if (lane == 0) knn[t] = bj & (N_PTS - 1);
        int owner = (bj >> 2) & 63;
        if (lane == owner) {
            int cw = (((bj >> 8) << 2) | (bj & 3)) & 63;
            taken |= (1ull << cw);
            v0 = v1; c0 = c1; v1 = v2; c1 = c2; v2 = 1e30f; c2 = -1;
            if (v0 >= 1e30f) {
                v0 = v1 = v2 = 1e30f; c0 = c1 = c2 = -1;
                for (int s = 0; s < 16; ++s) {
                    int jb = s * 256 + lane * 4;
                    float4 fx = *(const float4*)(xb + jb);
                    float4 fy = *(const float4*)(xb + N_PTS + jb);
                    float4 fz = *(const float4*)(xb + 2 * N_PTS + jb);
#pragma unroll
                    for (int q = 0; q < 4; ++q) {
                        int cc = s * 4 + q;
                        if ((taken >> cc) & 1ull) continue;
                        int j = jb + q;
                        if (j == i) continue;
                        float xj = (q == 0) ? fx.x : (q == 1) ? fx.y : (q == 2) ? fx.z : fx.w;
                        float yj = (q == 0) ? fy.x : (q == 1) ? fy.y : (q == 2) ? fy.z : fy.w;
                        float zj = (q == 0) ? fz.x : (q == 1) ? fz.y : (q == 2) ? fz.z : fz.w;
                        float d = dist_exact(xi, yi, zi, sqi, xj, yj, zj);
                        insert3(d, cc, v0, v1, v2, c0, c1, c2);
                    }
                }
            }
        }
    }

    __syncthreads();

    __shared__ float aggf[FIN + 1];
    __shared__ float hif[FIN + 1];

    const float* xfb = xfeat + ((size_t)b * 64 + lane) * N_PTS;
    const float* xlb = xb + (size_t)(lane < 3 ? lane : 0) * N_PTS;
    float af = 0.f, al = 0.f;
    for (int t = 0; t < KNN; ++t) {
        int j = knn[t];
        af += xfb[j];
        if (lane < 3) al += xlb[j];
    }
    aggf[3 + lane] = af;
    hif[3 + lane]  = xfb[i];
    if (lane < 3) { aggf[lane] = al; hif[lane] = xlb[i]; }
    __syncthreads();

    float acc_rel = 0.f, acc_root = 0.f;
    for (int f = 0; f < FIN; ++f) {
        acc_rel  += aggf[f] * Wrel[f * COUT + lane];
        acc_root += hif[f]  * Wroot[f * COUT + lane];
    }
    float acc = (acc_rel + brel[lane]) + acc_root;
    acc = fmaxf(acc, 0.0f);
    out[(size_t)NB * 3 * N_PTS + ((((size_t)b << 6) | lane) << 12) + i] = acc;
}

extern "C" void kernel_launch(void* const* d_in, const int* in_sizes, int n_in,
                              void* d_out, int out_size, void* d_ws, size_t ws_size,
                              hipStream_t stream) {
    const float* xloc  = nullptr;
    const float* xfeat = nullptr;
    const float* Wrel  = nullptr;
    const float* brel  = nullptr;
    const float* Wroot = nullptr;
    for (int idx = 0; idx < n_in; ++idx) {
        const long long s = in_sizes[idx];
        const float* p = (const float*)d_in[idx];
        if (s == 98304LL || s == 393216LL)          { xloc = p; }
        else if (s == 2097152LL || s == 8388608LL)  { xfeat = p; }
        else if (s == 4288LL || s == 17152LL)       { if (!Wrel) Wrel = p; else Wroot = p; }
        else if (s == 64LL || s == 256LL)           { brel = p; }
    }
    if (!xloc || !xfeat || !Wrel || !brel || !Wroot) {
        xloc  = (const float*)d_in[0];
        xfeat = (const float*)d_in[1];
        Wrel  = (const float*)d_in[2];
        brel  = (const float*)d_in[3];
        Wroot = (const float*)d_in[4];
    }

    if (d_ws != nullptr && ws_size >= (size_t)WS_NEED) {
        u16*    knn_ws = (u16*)d_ws;
        float*  ft     = (float*)((char*)d_ws + FT_OFF);
        float4* pack   = (float4*)((char*)d_ws + PK_OFF);
        transpose_kernel<<<dim3(NB * 64), dim3(256), 0, stream>>>(
            xloc, xfeat, ft, pack, (float*)d_out);
        knn_v4_kernel<<<dim3(NB * 64), dim3(BT), 0, stream>>>(pack, knn_ws);
        conv_g2_kernel<<<dim3(NB * 256), dim3(128), 0, stream>>>(
            Wrel, brel, Wroot, knn_ws, ft, pack, (float*)d_out);
    } else if (d_ws != nullptr && ws_size >= (size_t)KNN_BYTES) {
        u16* knn_ws = (u16*)d_ws;
        knn_seg8_kernel<<<dim3(NB * 128), dim3(256), 0, stream>>>(xloc, knn_ws);
        conv_q_kernel<<<dim3(NB * 128), dim3(128), 0, stream>>>(
            xloc, xfeat, Wrel, brel, Wroot, knn_ws, (float*)d_out);
    } else {
        pcd_all<<<dim3(NB * N_PTS), dim3(64), 0, stream>>>(
            xloc, xfeat, Wrel, brel, Wroot, (float*)d_out);
    }
}

// Round 19
// 261.420 us; speedup vs baseline: 1.2894x; 1.2894x over previous
//
#include <hip/hip_runtime.h>

#define N_PTS 4096
#define NB    8
#define KNN   20
#define FIN   67
#define COUT  64
#define SEG   8
#define SEGN  (N_PTS / SEG)   // 512 candidates per segment-wave
#define SLOTS 16              // LDS stack slots per thread
#define BT    512             // knn block threads (8 waves)

typedef unsigned short u16;
typedef unsigned int   u32;
typedef unsigned long long u64;

// ws layout (bytes)
#define KNN_BYTES 1310720u                      // 8*4096*20*2
#define FT_OFF    1310720u                      // ft[b][n][64] f32 = 8388608
#define PK_OFF    (FT_OFF + 8388608u)           // pack[b][n] float4 = 524288
#define WS_NEED   (PK_OFF + 524288u)            // 10223616

__device__ __forceinline__ float finf() { return __uint_as_float(0x7f800000u); }

// Order-preserving f32 -> u32 map (total order, matches IEEE < on non-NaN).
__device__ __forceinline__ u32 fmap(float f) {
    u32 b = __float_as_uint(f);
    return b ^ ((u32)((int)b >> 31) | 0x80000000u);
}

// sq = (x*x + y*y) + z*z, all f32, no FMA (matches np op order).
__device__ __forceinline__ float sq_exact(float x, float y, float z) {
#pragma clang fp contract(off)
    float s = (x * x + y * y) + z * z;
    return s;
}

// dist = (sq_i - 2*dot) + sq_j, dot = (x_i*x_j + y_i*y_j) + z_i*z_j, no FMA.
__device__ __forceinline__ float dist_from_sq(float xi, float yi, float zi, float sqi,
                                              float xj, float yj, float zj, float sqj) {
#pragma clang fp contract(off)
    float d0 = xi * xj, d1 = yi * yj, d2 = zi * zj;
    float dot = (d0 + d1) + d2;
    float d = (sqi - 2.0f * dot) + sqj;
    return d;
}

__device__ __forceinline__ float dist_exact(float xi, float yi, float zi, float sqi,
                                            float xj, float yj, float zj) {
#pragma clang fp contract(off)
    float d0 = xi * xj, d1 = yi * yj, d2 = zi * zj;
    float dot = (d0 + d1) + d2;
    float sqj = (xj * xj + yj * yj) + zj * zj;
    float d = (sqi - 2.0f * dot) + sqj;
    return d;
}

// u64 key = fmap(d) << 12 | j  — plain u64 < is EXACT (d, j) lex order.
__device__ __forceinline__ void cswap64(u64& a, u64& b) {
    bool sw = b < a;
    u64 na = sw ? b : a, nb = sw ? a : b;
    a = na; b = nb;
}

// ---------------- Kernel 0: transpose/pack + out0 passthrough ----------------
__global__ __launch_bounds__(256) void transpose_kernel(
    const float* __restrict__ xloc, const float* __restrict__ xfeat,
    float* __restrict__ ft, float4* __restrict__ pack, float* __restrict__ out) {
    __shared__ float tile[64][65];
    const int tid = threadIdx.x;
    const int blk = blockIdx.x;               // b*64 + ntile
    const int b   = blk >> 6;
    const int n0  = (blk & 63) << 6;
    const int tx  = tid & 63, w = tid >> 6;

    if (tid < 48) {
        int idx4 = blk * 48 + tid;            // 512*48 float4 = 98304 f32
        ((float4*)out)[idx4] = ((const float4*)xloc)[idx4];
    }
    if (w == 0) {
        float x = xloc[((size_t)b * 3 + 0) * N_PTS + n0 + tx];
        float y = xloc[((size_t)b * 3 + 1) * N_PTS + n0 + tx];
        float z = xloc[((size_t)b * 3 + 2) * N_PTS + n0 + tx];
        pack[((size_t)b << 12) + n0 + tx] = make_float4(x, y, z, sq_exact(x, y, z));
    }
#pragma unroll
    for (int k = 0; k < 16; ++k) {
        int c = w * 16 + k;
        tile[tx][c] = xfeat[((size_t)(b << 6) + c) * N_PTS + n0 + tx];
    }
    __syncthreads();
#pragma unroll
    for (int k = 0; k < 16; ++k) {
        int n = w * 16 + k;
        ft[(((size_t)(b << 12)) + n0 + n) * 64 + tx] = tile[n][tx];
    }
}

// ---------------- Kernel 1: kNN v5 — shared threshold, LDS-neutral ----------
// v4 idea (cross-segment per-query threshold) with the LDS blunder fixed:
// thrS ALIASES the first 256 B of ext[] (dead during the scan phase), so
// LDS stays 81920 B -> 2 blocks/CU (v4's 82432 B halved residency).
// A __syncthreads() after the drain merge ensures no wave publishes into
// ext (overwriting thrS) while another is still scanning/reading it.
// Gate: d <= thr, thr = min over segments of their 21st-best-so-far.
// Exactness: rejected => d > v (some segment's 21st-smallest) => >=21
// candidates (>=20 non-self) strictly better => global non-self rank >= 21.
// Races on thrS only loosen it (writes are genuine 21st-best values).
__global__ __launch_bounds__(BT) void knn_v5_kernel(
    const float4* __restrict__ pack, u16* __restrict__ knn_out) {
    __shared__ u64 stk[SLOTS][BT];            // 64 KB, bank-free SoA
    __shared__ u64 ext[KNN - SLOTS][BT];      // 16 KB (publish slots 16..19)
    float* thrS = (float*)&ext[0][0];         // 256 B alias, scan phase only
    volatile float* vthr = thrS;
    const int tid  = threadIdx.x;
    const int lane = tid & 63;                // query within tile
    const int blk  = blockIdx.x;              // b*64 + qtile
    const int b    = blk >> 6;
    const int tile = blk & 63;
    const int i    = (tile << 6) | lane;
    const float4* pb = pack + ((size_t)b << 12);

    if (tid < 64) thrS[tid] = finf();

    // Wave-uniform segment base -> scalar loads in the hot loop.
    const int segu  = __builtin_amdgcn_readfirstlane(tid >> 6);
    const float4* base = pb + segu * SEGN;

    const float4 qp = pb[i];
    const float xi = qp.x, yi = qp.y, zi = qp.z, sqi = qp.w;

    __syncthreads();                          // thrS initialized

    u64 ld[32];
#pragma unroll
    for (int t = 0; t < 32; ++t) ld[t] = ~0ull;
    float thr = finf();
    int cnt = 0;

    auto merge_stack = [&]() {
        u64 bd[SLOTS];
#pragma unroll
        for (int t = 0; t < SLOTS; ++t) bd[t] = (t < cnt) ? stk[t][tid] : ~0ull;
#pragma unroll
        for (int k = 2; k <= SLOTS; k <<= 1) {
#pragma unroll
            for (int s = k >> 1; s > 0; s >>= 1) {
#pragma unroll
                for (int t = 0; t < SLOTS; ++t) {
                    int l = t ^ s;
                    if (l > t) {
                        if ((t & k) == 0) cswap64(bd[t], bd[l]);
                        else              cswap64(bd[l], bd[t]);
                    }
                }
            }
        }
#pragma unroll
        for (int t = 0; t < SLOTS; ++t) cswap64(ld[31 - t], bd[t]);
#pragma unroll
        for (int k = 16; k >= 1; k >>= 1) {
#pragma unroll
            for (int t = 0; t < 32; ++t) {
                if ((t & k) == 0) cswap64(ld[t], ld[t | k]);
            }
        }
        // own 21st-best distance (ld[KNN]); guard padding (all-ones).
        u32 m = (u32)(ld[KNN] >> 12);
        u32 db = m ^ ((m & 0x80000000u) ? 0x80000000u : 0xFFFFFFFFu);
        float own = (m == 0xFFFFFFFFu) ? finf() : __uint_as_float(db);
        // Fold into the shared per-query threshold (racy but monotone-safe).
        float sh = vthr[lane];
        float nw = fminf(own, sh);
        vthr[lane] = nw;
        thr = nw;
        cnt = 0;
    };

    const int jbase = segu * SEGN;
    for (int c = 0; c < SEGN; c += 4) {
        // Refresh gate from the shared threshold (other segments tighten it).
        thr = fminf(thr, vthr[lane]);
        float4 p0 = base[c + 0], p1 = base[c + 1];
        float4 p2 = base[c + 2], p3 = base[c + 3];
#pragma unroll
        for (int qq = 0; qq < 4; ++qq) {
            float4 pk = (qq == 0) ? p0 : (qq == 1) ? p1 : (qq == 2) ? p2 : p3;
            float d = dist_from_sq(xi, yi, zi, sqi, pk.x, pk.y, pk.z, pk.w);
            // Gate d <= thr (equality ACCEPTED — required for cross-segment
            // sharing; see kernel comment for the exactness proof).
            if (d <= thr) {
                u64 key = ((u64)fmap(d) << 12) | (u32)(jbase + c + qq);
                stk[cnt][tid] = key;
                ++cnt;
            }
        }
        // Entering a chunk all lanes have cnt <= 12; +4 max => <= 16. ✓
        if (__any(cnt >= SLOTS - 3)) merge_stack();
    }
    merge_stack();                            // drain

    __syncthreads();                          // all scans done before thrS dies

    // Publish exact top-20 EXCLUDING self: compact ld[0..20] (exact top-21).
    u64 pub[KNN];
    {
        bool sf = false;
#pragma unroll
        for (int t = 0; t < KNN + 1; ++t) {
            bool isself = ((u32)(ld[t] & 0xFFFull) == (u32)i);
            sf = sf || isself;
            if (t < KNN) pub[t] = sf ? ld[t + 1] : ld[t];
        }
    }
#pragma unroll
    for (int t = 0; t < SLOTS; ++t) stk[t][tid] = pub[t];
#pragma unroll
    for (int t = SLOTS; t < KNN; ++t) ext[t - SLOTS][tid] = pub[t];
    __syncthreads();

    // Exact 8-way tournament merge per query (threads 0..63).
    if (tid < 64) {
        const int q = tid;
        const int row = (b << 12) | (tile << 6) | q;
        int pp[SEG];
        u64 kk[SEG];
#pragma unroll
        for (int s = 0; s < SEG; ++s) { pp[s] = 0; kk[s] = stk[0][q + 64 * s]; }
#pragma unroll
        for (int t = 0; t < KNN; ++t) {
            u64 best = kk[0]; int sm = 0;
#pragma unroll
            for (int s = 1; s < SEG; ++s)
                if (kk[s] < best) { best = kk[s]; sm = s; }
            knn_out[(size_t)row * KNN + t] = (u16)(best & 0xFFFull);
#pragma unroll
            for (int s = 0; s < SEG; ++s) {
                if (s == sm) {
                    int p = ++pp[s];
                    int col = q + 64 * s;
                    kk[s] = (p < KNN) ? ((p < SLOTS) ? stk[p][col] : ext[p - SLOTS][col])
                                      : ~0ull;
                }
            }
        }
    }
}

// ---------------- Kernel 2: conv — 16-pt tiles, LDS index preload ----------------
__global__ __launch_bounds__(128) void conv_g2_kernel(
    const float* __restrict__ Wrel,
    const float* __restrict__ brel,
    const float* __restrict__ Wroot,
    const u16* __restrict__ knn_in,
    const float* __restrict__ ft,
    const float4* __restrict__ pack,
    float* __restrict__ out) {
    __shared__ float aggf[16][69];
    __shared__ float hif[16][69];
    __shared__ u16 idx[16 * KNN];             // 640 B
    const int tid = threadIdx.x;
    const int blk = blockIdx.x;               // b*256 + tile
    const int b   = blk >> 8;
    const int i0  = (blk & 255) << 4;
    const int lane = tid & 63, w = tid >> 6;
    const float* ftb = ft + (((size_t)b << 12)) * 64;
    const float* pkb = (const float*)(pack + ((size_t)b << 12));

    {
        const u32* src = (const u32*)(knn_in + (size_t)((b << 12) | i0) * KNN);
        for (int k = tid; k < 16 * KNN / 2; k += 128) ((u32*)idx)[k] = src[k];
    }
    __syncthreads();

#pragma unroll
    for (int pp = 0; pp < 8; ++pp) {
        int p = w * 8 + pp;
        int i = i0 + p;
        float af = 0.f, al = 0.f;
        float hfv = ftb[(size_t)i * 64 + lane];
        float hlv = (lane < 3) ? pkb[(size_t)i * 4 + lane] : 0.f;
#pragma unroll
        for (int t = 0; t < KNN; ++t) {       // ascending (dist, idx) order
            int j = idx[p * KNN + t];
            af += ftb[(size_t)j * 64 + lane];
            if (lane < 3) al += pkb[(size_t)j * 4 + lane];
        }
        aggf[p][3 + lane] = af;
        hif[p][3 + lane]  = hfv;
        if (lane < 3) { aggf[p][lane] = al; hif[p][lane] = hlv; }
    }
    __syncthreads();

    const int p2 = tid & 15, oct = tid >> 4;  // 8 channels per thread
    const int i2 = i0 + p2;
    float rel[8], root[8];
#pragma unroll
    for (int c = 0; c < 8; ++c) { rel[c] = 0.f; root[c] = 0.f; }
    for (int f = 0; f < FIN; ++f) {
        float a = aggf[p2][f];
        float h = hif[p2][f];
        const float4* w4r = (const float4*)(Wrel + f * COUT + oct * 8);
        const float4* w4o = (const float4*)(Wroot + f * COUT + oct * 8);
#pragma unroll
        for (int c4 = 0; c4 < 2; ++c4) {
            float4 wr = w4r[c4], wo = w4o[c4];
            rel[c4 * 4 + 0] += a * wr.x;  root[c4 * 4 + 0] += h * wo.x;
            rel[c4 * 4 + 1] += a * wr.y;  root[c4 * 4 + 1] += h * wo.y;
            rel[c4 * 4 + 2] += a * wr.z;  root[c4 * 4 + 2] += h * wo.z;
            rel[c4 * 4 + 3] += a * wr.w;  root[c4 * 4 + 3] += h * wo.w;
        }
    }
    const size_t ob = (size_t)NB * 3 * N_PTS + (size_t)b * COUT * N_PTS;
#pragma unroll
    for (int c = 0; c < 8; ++c) {
        int cc = oct * 8 + c;
        float acc = (rel[c] + brel[cc]) + root[c];  // einsum + b_rel + einsum order
        out[ob + (size_t)cc * N_PTS + i2] = fmaxf(acc, 0.f);
    }
}

// ================= r14 fallback path (proven, 379us) =================
__global__ __launch_bounds__(256) void knn_seg8_kernel(
    const float* __restrict__ xloc, u16* __restrict__ knn_out) {
    __shared__ u64 stk[SLOTS][256];
    __shared__ u64 ext[KNN - SLOTS][256];
    const int tid  = threadIdx.x;
    const int q    = tid & 31;
    const int seg  = tid >> 5;
    const int blk  = blockIdx.x;
    const int b    = blk >> 7;
    const int i    = ((blk & 127) << 5) | q;
    const float* xb = xloc + (size_t)b * 3 * N_PTS;

    const float xi = xb[i], yi = xb[N_PTS + i], zi = xb[2 * N_PTS + i];
    const float sqi = sq_exact(xi, yi, zi);

    u64 ld[32];
#pragma unroll
    for (int t = 0; t < 32; ++t) ld[t] = ~0ull;
    u64 thr = ~0ull;
    int cnt = 0;

    auto merge_stack = [&]() {
        u64 bd[SLOTS];
#pragma unroll
        for (int t = 0; t < SLOTS; ++t) bd[t] = (t < cnt) ? stk[t][tid] : ~0ull;
#pragma unroll
        for (int k = 2; k <= SLOTS; k <<= 1) {
#pragma unroll
            for (int s = k >> 1; s > 0; s >>= 1) {
#pragma unroll
                for (int t = 0; t < SLOTS; ++t) {
                    int l = t ^ s;
                    if (l > t) {
                        if ((t & k) == 0) cswap64(bd[t], bd[l]);
                        else              cswap64(bd[l], bd[t]);
                    }
                }
            }
        }
#pragma unroll
        for (int t = 0; t < SLOTS; ++t) cswap64(ld[31 - t], bd[t]);
#pragma unroll
        for (int k = 16; k >= 1; k >>= 1) {
#pragma unroll
            for (int t = 0; t < 32; ++t) {
                if ((t & k) == 0) cswap64(ld[t], ld[t | k]);
            }
        }
        thr = ld[KNN - 1];
        cnt = 0;
    };

    const int cbase = seg * 512;
    for (int c = 0; c < 512; c += 4) {
        const int cc = cbase + c;
        float4 fx = *(const float4*)(xb + cc);
        float4 fy = *(const float4*)(xb + N_PTS + cc);
        float4 fz = *(const float4*)(xb + 2 * N_PTS + cc);
#pragma unroll
        for (int qq = 0; qq < 4; ++qq) {
            float xj = (qq == 0) ? fx.x : (qq == 1) ? fx.y : (qq == 2) ? fx.z : fx.w;
            float yj = (qq == 0) ? fy.x : (qq == 1) ? fy.y : (qq == 2) ? fy.z : fy.w;
            float zj = (qq == 0) ? fz.x : (qq == 1) ? fz.y : (qq == 2) ? fz.z : fz.w;
            float sqj = sq_exact(xj, yj, zj);
            float d = dist_from_sq(xi, yi, zi, sqi, xj, yj, zj, sqj);
            int j = cc + qq;
            u64 key = ((u64)fmap(d) << 12) | (u32)j;
            bool ok = (j != i) && (key < thr);
            if (ok) { stk[cnt][tid] = key; ++cnt; }
        }
        if (__any(cnt >= SLOTS - 3)) merge_stack();
    }
    merge_stack();

#pragma unroll
    for (int t = 0; t < SLOTS; ++t) stk[t][tid] = ld[t];
#pragma unroll
    for (int t = SLOTS; t < KNN; ++t) ext[t - SLOTS][tid] = ld[t];
    __syncthreads();

    if (tid < 32) {
        const int col0 = tid;
        const int row  = (b << 12) | ((blk & 127) << 5) | tid;
        int  pp[8];
        u64  kk[8];
#pragma unroll
        for (int s = 0; s < 8; ++s) { pp[s] = 0; kk[s] = stk[0][col0 + 32 * s]; }
#pragma unroll
        for (int t = 0; t < KNN; ++t) {
            u64 best = kk[0]; int sm = 0;
#pragma unroll
            for (int s = 1; s < 8; ++s)
                if (kk[s] < best) { best = kk[s]; sm = s; }
            knn_out[(size_t)row * KNN + t] = (u16)(best & 0xFFFu);
#pragma unroll
            for (int s = 0; s < 8; ++s) {
                if (s == sm) {
                    int p = ++pp[s];
                    int col = col0 + 32 * s;
                    kk[s] = (p < KNN) ? ((p < SLOTS) ? stk[p][col] : ext[p - SLOTS][col])
                                      : ~0ull;
                }
            }
        }
    }
}

__global__ __launch_bounds__(128) void conv_q_kernel(
    const float* __restrict__ xloc,
    const float* __restrict__ xfeat,
    const float* __restrict__ Wrel,
    const float* __restrict__ brel,
    const float* __restrict__ Wroot,
    const u16* __restrict__ knn_in,
    float* __restrict__ out) {
    __shared__ float rowbuf[2][N_PTS];
    const int tid = threadIdx.x;
    const int p   = tid & 31;
    const int qtr = tid >> 5;
    const int blk = blockIdx.x;
    const int b   = blk >> 7;
    const int i   = ((blk & 127) << 5) | p;
    const float* xb = xloc + (size_t)b * 3 * N_PTS;
    const float* fb = xfeat + (size_t)b * 64 * N_PTS;

    if (qtr == 0) {
#pragma unroll
        for (int c = 0; c < 3; ++c)
            out[((size_t)b * 3 + c) * N_PTS + i] = xb[(size_t)c * N_PTS + i];
    }

    u32 kl[KNN / 2];
    const u32* kp = (const u32*)(knn_in + (size_t)((b << 12) | i) * KNN);
#pragma unroll
    for (int w = 0; w < KNN / 2; ++w) kl[w] = kp[w];
    int jj[KNN];
#pragma unroll
    for (int t = 0; t < KNN; ++t) jj[t] = (int)((kl[t >> 1] >> ((t & 1) * 16)) & 0xFFFFu);

    float rel[16], root[16];
#pragma unroll
    for (int c = 0; c < 16; ++c) { rel[c] = 0.f; root[c] = 0.f; }

    auto stage = [&](int f) {
        const float* src = (f < 3) ? (xb + (size_t)f * N_PTS)
                                   : (fb + (size_t)(f - 3) * N_PTS);
        const float4* s4 = (const float4*)src;
        float4* d4 = (float4*)rowbuf[f & 1];
#pragma unroll
        for (int w = 0; w < 8; ++w) {
            int idxw = w * 128 + tid;
            d4[idxw] = s4[idxw];
        }
    };

    stage(0);
    __syncthreads();

    for (int f = 0; f < FIN; ++f) {
        if (f + 1 < FIN) stage(f + 1);
        const float* cur = rowbuf[f & 1];
        float hf = cur[i];
        float af = 0.f;
#pragma unroll
        for (int t = 0; t < KNN; ++t) af += cur[jj[t]];

        const float4* w4r = (const float4*)(Wrel + f * COUT + qtr * 16);
        const float4* w4o = (const float4*)(Wroot + f * COUT + qtr * 16);
#pragma unroll
        for (int c4 = 0; c4 < 4; ++c4) {
            float4 wr = w4r[c4], wo = w4o[c4];
            rel[c4 * 4 + 0] += af * wr.x;  root[c4 * 4 + 0] += hf * wo.x;
            rel[c4 * 4 + 1] += af * wr.y;  root[c4 * 4 + 1] += hf * wo.y;
            rel[c4 * 4 + 2] += af * wr.z;  root[c4 * 4 + 2] += hf * wo.z;
            rel[c4 * 4 + 3] += af * wr.w;  root[c4 * 4 + 3] += hf * wo.w;
        }
        __syncthreads();
    }

    const size_t ob = (size_t)NB * 3 * N_PTS + (size_t)b * COUT * N_PTS;
#pragma unroll
    for (int c = 0; c < 16; ++c) {
        int cc = qtr * 16 + c;
        float acc = (rel[c] + brel[cc]) + root[c];
        out[ob + (size_t)cc * N_PTS + i] = fmaxf(acc, 0.f);
    }
}

// ---------------- Last-resort fallback: proven round-7 monolith ----------------
__device__ __forceinline__ void insert3(float d, int c,
                                        float& v0, float& v1, float& v2,
                                        int& c0, int& c1, int& c2) {
    if (d < v2) {
        if (d < v1) {
            if (d < v0) { v2 = v1; c2 = c1; v1 = v0; c1 = c0; v0 = d; c0 = c; }
            else        { v2 = v1; c2 = c1; v1 = d;  c1 = c; }
        } else          { v2 = d;  c2 = c; }
    }
}

__global__ __launch_bounds__(64) void pcd_all(
    const float* __restrict__ xloc,
    const float* __restrict__ xfeat,
    const float* __restrict__ Wrel,
    const float* __restrict__ brel,
    const float* __restrict__ Wroot,
    float* __restrict__ out) {
    const int lane = threadIdx.x;
    const int row  = blockIdx.x;
    const int b    = row >> 12;
    const int i    = row & (N_PTS - 1);
    const float* xb = xloc + (size_t)b * 3 * N_PTS;

    if (lane < 3) {
        out[((size_t)b * 3 + lane) * N_PTS + i] = xb[(size_t)lane * N_PTS + i];
    }

    const float xi  = xb[i];
    const float yi  = xb[N_PTS + i];
    const float zi  = xb[2 * N_PTS + i];
    const float sqi = sq_exact(xi, yi, zi);

    float v0 = 1e30f, v1 = 1e30f, v2 = 1e30f;
    int   c0 = -1,    c1 = -1,    c2 = -1;

    for (int s = 0; s < 16; ++s) {
        int jb = s * 256 + lane * 4;
        float4 fx = *(const float4*)(xb + jb);
        float4 fy = *(const float4*)(xb + N_PTS + jb);
        float4 fz = *(const float4*)(xb + 2 * N_PTS + jb);
#pragma unroll
        for (int q = 0; q < 4; ++q) {
            float xj = (q == 0) ? fx.x : (q == 1) ? fx.y : (q == 2) ? fx.z : fx.w;
            float yj = (q == 0) ? fy.x : (q == 1) ? fy.y : (q == 2) ? fy.z : fy.w;
            float zj = (q == 0) ? fz.x : (q == 1) ? fz.y : (q == 2) ? fz.z : fz.w;
            int j = jb + q;
            float d = (j == i) ? 1e30f : dist_exact(xi, yi, zi, sqi, xj, yj, zj);
            insert3(d, s * 4 + q, v0, v1, v2, c0, c1, c2);
        }
    }

    u64 taken = 0;
    __shared__ int knn[KNN];

    for (int t = 0; t < KNN; ++t) {
        float bv = v0;
        int   bj = (c0 >= 0) ? (((c0 >> 2) << 8) + lane * 4 + (c0 & 3)) : (N_PTS - 1);
#pragma unroll
        for (int m = 1; m < 64; m <<= 1) {
            float ov = __shfl_xor(bv, m);
            int   oj = __shfl_xor(bj, m);
            if (ov < bv || (ov == bv && oj < bj)) { bv = ov; bj = oj; }
        }
        if (lane == 0) knn[t] = bj & (N_PTS - 1);
        int owner = (bj >> 2) & 63;
        if (lane == owner) {
            int cw = (((bj >> 8) << 2) | (bj & 3)) & 63;
            taken |= (1ull << cw);
            v0 = v1; c0 = c1; v1 = v2; c1 = c2; v2 = 1e30f; c2 = -1;
            if (v0 >= 1e30f) {
                v0 = v1 = v2 = 1e30f; c0 = c1 = c2 = -1;
                for (int s = 0; s < 16; ++s) {
                    int jb = s * 256 + lane * 4;
                    float4 fx = *(const float4*)(xb + jb);
                    float4 fy = *(const float4*)(xb + N_PTS + jb);
                    float4 fz = *(const float4*)(xb + 2 * N_PTS + jb);
#pragma unroll
                    for (int q = 0; q < 4; ++q) {
                        int cc = s * 4 + q;
                        if ((taken >> cc) & 1ull) continue;
                        int j = jb + q;
                        if (j == i) continue;
                        float xj = (q == 0) ? fx.x : (q == 1) ? fx.y : (q == 2) ? fx.z : fx.w;
                        float yj = (q == 0) ? fy.x : (q == 1) ? fy.y : (q == 2) ? fy.z : fy.w;
                        float zj = (q == 0) ? fz.x : (q == 1) ? fz.y : (q == 2) ? fz.z : fz.w;
                        float d = dist_exact(xi, yi, zi, sqi, xj, yj, zj);
                        insert3(d, cc, v0, v1, v2, c0, c1, c2);
                    }
                }
            }
        }
    }

    __syncthreads();

    __shared__ float aggf[FIN + 1];
    __shared__ float hif[FIN + 1];

    const float* xfb = xfeat + ((size_t)b * 64 + lane) * N_PTS;
    const float* xlb = xb + (size_t)(lane < 3 ? lane : 0) * N_PTS;
    float af = 0.f, al = 0.f;
    for (int t = 0; t < KNN; ++t) {
        int j = knn[t];
        af += xfb[j];
        if (lane < 3) al += xlb[j];
    }
    aggf[3 + lane] = af;
    hif[3 + lane]  = xfb[i];
    if (lane < 3) { aggf[lane] = al; hif[lane] = xlb[i]; }
    __syncthreads();

    float acc_rel = 0.f, acc_root = 0.f;
    for (int f = 0; f < FIN; ++f) {
        acc_rel  += aggf[f] * Wrel[f * COUT + lane];
        acc_root += hif[f]  * Wroot[f * COUT + lane];
    }
    float acc = (acc_rel + brel[lane]) + acc_root;
    acc = fmaxf(acc, 0.0f);
    out[(size_t)NB * 3 * N_PTS + ((((size_t)b << 6) | lane) << 12) + i] = acc;
}

extern "C" void kernel_launch(void* const* d_in, const int* in_sizes, int n_in,
                              void* d_out, int out_size, void* d_ws, size_t ws_size,
                              hipStream_t stream) {
    const float* xloc  = nullptr;
    const float* xfeat = nullptr;
    const float* Wrel  = nullptr;
    const float* brel  = nullptr;
    const float* Wroot = nullptr;
    for (int idx = 0; idx < n_in; ++idx) {
        const long long s = in_sizes[idx];
        const float* p = (const float*)d_in[idx];
        if (s == 98304LL || s == 393216LL)          { xloc = p; }
        else if (s == 2097152LL || s == 8388608LL)  { xfeat = p; }
        else if (s == 4288LL || s == 17152LL)       { if (!Wrel) Wrel = p; else Wroot = p; }
        else if (s == 64LL || s == 256LL)           { brel = p; }
    }
    if (!xloc || !xfeat || !Wrel || !brel || !Wroot) {
        xloc  = (const float*)d_in[0];
        xfeat = (const float*)d_in[1];
        Wrel  = (const float*)d_in[2];
        brel  = (const float*)d_in[3];
        Wroot = (const float*)d_in[4];
    }

    if (d_ws != nullptr && ws_size >= (size_t)WS_NEED) {
        u16*    knn_ws = (u16*)d_ws;
        float*  ft     = (float*)((char*)d_ws + FT_OFF);
        float4* pack   = (float4*)((char*)d_ws + PK_OFF);
        transpose_kernel<<<dim3(NB * 64), dim3(256), 0, stream>>>(
            xloc, xfeat, ft, pack, (float*)d_out);
        knn_v5_kernel<<<dim3(NB * 64), dim3(BT), 0, stream>>>(pack, knn_ws);
        conv_g2_kernel<<<dim3(NB * 256), dim3(128), 0, stream>>>(
            Wrel, brel, Wroot, knn_ws, ft, pack, (float*)d_out);
    } else if (d_ws != nullptr && ws_size >= (size_t)KNN_BYTES) {
        u16* knn_ws = (u16*)d_ws;
        knn_seg8_kernel<<<dim3(NB * 128), dim3(256), 0, stream>>>(xloc, knn_ws);
        conv_q_kernel<<<dim3(NB * 128), dim3(128), 0, stream>>>(
            xloc, xfeat, Wrel, brel, Wroot, knn_ws, (float*)d_out);
    } else {
        pcd_all<<<dim3(NB * N_PTS), dim3(64), 0, stream>>>(
            xloc, xfeat, Wrel, brel, Wroot, (float*)d_out);
    }
}

// Round 20
// 253.015 us; speedup vs baseline: 1.3322x; 1.0332x over previous
//
#include <hip/hip_runtime.h>

#define N_PTS 4096
#define NB    8
#define KNN   20
#define FIN   67
#define COUT  64
#define SEG   8
#define SEGN  (N_PTS / SEG)   // 512 candidates per segment-wave
#define SLOTS 16              // LDS stack slots per thread
#define BT    512             // knn block threads (8 waves)

typedef unsigned short u16;
typedef unsigned int   u32;
typedef unsigned long long u64;

// ws layout (bytes)
#define KNN_BYTES 1310720u                      // 8*4096*20*2
#define FT_OFF    1310720u                      // ft[b][n][64] f32 = 8388608
#define PK_OFF    (FT_OFF + 8388608u)           // pack[b][n] float4 = 524288
#define WS_NEED   (PK_OFF + 524288u)            // 10223616

__device__ __forceinline__ float finf() { return __uint_as_float(0x7f800000u); }

// Order-preserving f32 -> u32 map (total order, matches IEEE < on non-NaN).
__device__ __forceinline__ u32 fmap(float f) {
    u32 b = __float_as_uint(f);
    return b ^ ((u32)((int)b >> 31) | 0x80000000u);
}

// sq = (x*x + y*y) + z*z, all f32, no FMA (matches np op order).
__device__ __forceinline__ float sq_exact(float x, float y, float z) {
#pragma clang fp contract(off)
    float s = (x * x + y * y) + z * z;
    return s;
}

// dist = (sq_i - 2*dot) + sq_j, dot = (x_i*x_j + y_i*y_j) + z_i*z_j, no FMA.
__device__ __forceinline__ float dist_from_sq(float xi, float yi, float zi, float sqi,
                                              float xj, float yj, float zj, float sqj) {
#pragma clang fp contract(off)
    float d0 = xi * xj, d1 = yi * yj, d2 = zi * zj;
    float dot = (d0 + d1) + d2;
    float d = (sqi - 2.0f * dot) + sqj;
    return d;
}

__device__ __forceinline__ float dist_exact(float xi, float yi, float zi, float sqi,
                                            float xj, float yj, float zj) {
#pragma clang fp contract(off)
    float d0 = xi * xj, d1 = yi * yj, d2 = zi * zj;
    float dot = (d0 + d1) + d2;
    float sqj = (xj * xj + yj * yj) + zj * zj;
    float d = (sqi - 2.0f * dot) + sqj;
    return d;
}

// u64 key = fmap(d) << 12 | j  — plain u64 < is EXACT (d, j) lex order.
__device__ __forceinline__ void cswap64(u64& a, u64& b) {
    bool sw = b < a;
    u64 na = sw ? b : a, nb = sw ? a : b;
    a = na; b = nb;
}

// ---------------- Kernel 0: transpose/pack + out0 passthrough ----------------
__global__ __launch_bounds__(256) void transpose_kernel(
    const float* __restrict__ xloc, const float* __restrict__ xfeat,
    float* __restrict__ ft, float4* __restrict__ pack, float* __restrict__ out) {
    __shared__ float tile[64][65];
    const int tid = threadIdx.x;
    const int blk = blockIdx.x;               // b*64 + ntile
    const int b   = blk >> 6;
    const int n0  = (blk & 63) << 6;
    const int tx  = tid & 63, w = tid >> 6;

    if (tid < 48) {
        int idx4 = blk * 48 + tid;            // 512*48 float4 = 98304 f32
        ((float4*)out)[idx4] = ((const float4*)xloc)[idx4];
    }
    if (w == 0) {
        float x = xloc[((size_t)b * 3 + 0) * N_PTS + n0 + tx];
        float y = xloc[((size_t)b * 3 + 1) * N_PTS + n0 + tx];
        float z = xloc[((size_t)b * 3 + 2) * N_PTS + n0 + tx];
        pack[((size_t)b << 12) + n0 + tx] = make_float4(x, y, z, sq_exact(x, y, z));
    }
#pragma unroll
    for (int k = 0; k < 16; ++k) {
        int c = w * 16 + k;
        tile[tx][c] = xfeat[((size_t)(b << 6) + c) * N_PTS + n0 + tx];
    }
    __syncthreads();
#pragma unroll
    for (int k = 0; k < 16; ++k) {
        int n = w * 16 + k;
        ft[(((size_t)(b << 12)) + n0 + n) * 64 + tx] = tile[n][tx];
    }
}

// ---------------- Kernel 1: kNN v6 — LDS-staged candidates ----------
// v5 (shared threshold, 2 blocks/CU) + the scan's candidate feed switched
// from scalar s_loads (128 dependent K$-missing loads/wave — the r19 stall)
// to: per-64-candidate chunk, one coalesced per-lane vector load (prefetched
// a chunk ahead) + ds_write_b128 + lgkmcnt(0); candidates consumed via
// wave-uniform broadcast ds_read_b128 (conflict-free). The 8 KB candbuf and
// thrS alias ext[] (dead during scan; the pre-publish __syncthreads() makes
// aliasing safe) -> LDS stays 81920 B.
__global__ __launch_bounds__(BT) void knn_v6_kernel(
    const float4* __restrict__ pack, u16* __restrict__ knn_out) {
    __shared__ u64 stk[SLOTS][BT];            // 64 KB, bank-free SoA
    __shared__ u64 ext[KNN - SLOTS][BT];      // 16 KB (publish; aliased in scan)
    float* thrS = (float*)&ext[0][0];         // 256 B alias, scan phase only
    volatile float* vthr = thrS;
    const int tid  = threadIdx.x;
    const int lane = tid & 63;                // query within tile
    const int wv   = tid >> 6;                // wave = segment
    const int blk  = blockIdx.x;              // b*64 + qtile
    const int b    = blk >> 6;
    const int tile = blk & 63;
    const int i    = (tile << 6) | lane;
    const float4* pb = pack + ((size_t)b << 12);

    // Per-wave 64-candidate staging buffer (1 KB each), after thrS in ext.
    float4* mycand = (float4*)((char*)&ext[0][0] + 256) + wv * 64;

    if (tid < 64) thrS[tid] = finf();

    const float4* base = pb + wv * SEGN;

    const float4 qp = pb[i];
    const float xi = qp.x, yi = qp.y, zi = qp.z, sqi = qp.w;

    __syncthreads();                          // thrS initialized

    u64 ld[32];
#pragma unroll
    for (int t = 0; t < 32; ++t) ld[t] = ~0ull;
    float thr = finf();
    int cnt = 0;

    auto merge_stack = [&]() {
        u64 bd[SLOTS];
#pragma unroll
        for (int t = 0; t < SLOTS; ++t) bd[t] = (t < cnt) ? stk[t][tid] : ~0ull;
#pragma unroll
        for (int k = 2; k <= SLOTS; k <<= 1) {
#pragma unroll
            for (int s = k >> 1; s > 0; s >>= 1) {
#pragma unroll
                for (int t = 0; t < SLOTS; ++t) {
                    int l = t ^ s;
                    if (l > t) {
                        if ((t & k) == 0) cswap64(bd[t], bd[l]);
                        else              cswap64(bd[l], bd[t]);
                    }
                }
            }
        }
#pragma unroll
        for (int t = 0; t < SLOTS; ++t) cswap64(ld[31 - t], bd[t]);
#pragma unroll
        for (int k = 16; k >= 1; k >>= 1) {
#pragma unroll
            for (int t = 0; t < 32; ++t) {
                if ((t & k) == 0) cswap64(ld[t], ld[t | k]);
            }
        }
        // own 21st-best distance (ld[KNN]); guard padding (all-ones).
        u32 m = (u32)(ld[KNN] >> 12);
        u32 db = m ^ ((m & 0x80000000u) ? 0x80000000u : 0xFFFFFFFFu);
        float own = (m == 0xFFFFFFFFu) ? finf() : __uint_as_float(db);
        // Fold into the shared per-query threshold (racy but monotone-safe).
        float sh = vthr[lane];
        float nw = fminf(own, sh);
        vthr[lane] = nw;
        thr = nw;
        cnt = 0;
    };

    const int jbase = wv * SEGN;
    float4 nxt = base[lane];                  // prefetch chunk 0 (vector load)
    for (int c0 = 0; c0 < SEGN; c0 += 64) {
        mycand[lane] = nxt;                   // ds_write_b128 (own slot)
        if (c0 + 64 < SEGN) nxt = base[c0 + 64 + lane];  // prefetch next chunk
        asm volatile("s_waitcnt lgkmcnt(0)" ::: "memory");  // stage visible

        for (int cc = 0; cc < 64; cc += 4) {
            // Refresh gate from the shared threshold.
            thr = fminf(thr, vthr[lane]);
            float4 p0 = mycand[cc + 0], p1 = mycand[cc + 1];
            float4 p2 = mycand[cc + 2], p3 = mycand[cc + 3];
#pragma unroll
            for (int qq = 0; qq < 4; ++qq) {
                float4 pk = (qq == 0) ? p0 : (qq == 1) ? p1 : (qq == 2) ? p2 : p3;
                float d = dist_from_sq(xi, yi, zi, sqi, pk.x, pk.y, pk.z, pk.w);
                // Gate d <= thr (equality ACCEPTED — cross-segment sharing;
                // rejected => d > some segment's 21st-smallest => >=20 non-self
                // strictly better => global non-self rank >= 21). Self (d=+0.0)
                // flows through; compacted out of the exact top-21 at publish.
                if (d <= thr) {
                    u64 key = ((u64)fmap(d) << 12) | (u32)(jbase + c0 + cc + qq);
                    stk[cnt][tid] = key;
                    ++cnt;
                }
            }
            // Entering a chunk all lanes have cnt <= 12; +4 max => <= 16. ✓
            if (__any(cnt >= SLOTS - 3)) merge_stack();
        }
    }
    merge_stack();                            // drain

    __syncthreads();                          // all scans done before ext reuse

    // Publish exact top-20 EXCLUDING self: compact ld[0..20] (exact top-21).
    u64 pub[KNN];
    {
        bool sf = false;
#pragma unroll
        for (int t = 0; t < KNN + 1; ++t) {
            bool isself = ((u32)(ld[t] & 0xFFFull) == (u32)i);
            sf = sf || isself;
            if (t < KNN) pub[t] = sf ? ld[t + 1] : ld[t];
        }
    }
#pragma unroll
    for (int t = 0; t < SLOTS; ++t) stk[t][tid] = pub[t];
#pragma unroll
    for (int t = SLOTS; t < KNN; ++t) ext[t - SLOTS][tid] = pub[t];
    __syncthreads();

    // Exact 8-way tournament merge per query (threads 0..63).
    if (tid < 64) {
        const int q = tid;
        const int row = (b << 12) | (tile << 6) | q;
        int pp[SEG];
        u64 kk[SEG];
#pragma unroll
        for (int s = 0; s < SEG; ++s) { pp[s] = 0; kk[s] = stk[0][q + 64 * s]; }
#pragma unroll
        for (int t = 0; t < KNN; ++t) {
            u64 best = kk[0]; int sm = 0;
#pragma unroll
            for (int s = 1; s < SEG; ++s)
                if (kk[s] < best) { best = kk[s]; sm = s; }
            knn_out[(size_t)row * KNN + t] = (u16)(best & 0xFFFull);
#pragma unroll
            for (int s = 0; s < SEG; ++s) {
                if (s == sm) {
                    int p = ++pp[s];
                    int col = q + 64 * s;
                    kk[s] = (p < KNN) ? ((p < SLOTS) ? stk[p][col] : ext[p - SLOTS][col])
                                      : ~0ull;
                }
            }
        }
    }
}

// ---------------- Kernel 2: conv — 16-pt tiles, LDS index preload ----------------
__global__ __launch_bounds__(128) void conv_g2_kernel(
    const float* __restrict__ Wrel,
    const float* __restrict__ brel,
    const float* __restrict__ Wroot,
    const u16* __restrict__ knn_in,
    const float* __restrict__ ft,
    const float4* __restrict__ pack,
    float* __restrict__ out) {
    __shared__ float aggf[16][69];
    __shared__ float hif[16][69];
    __shared__ u16 idx[16 * KNN];             // 640 B
    const int tid = threadIdx.x;
    const int blk = blockIdx.x;               // b*256 + tile
    const int b   = blk >> 8;
    const int i0  = (blk & 255) << 4;
    const int lane = tid & 63, w = tid >> 6;
    const float* ftb = ft + (((size_t)b << 12)) * 64;
    const float* pkb = (const float*)(pack + ((size_t)b << 12));

    {
        const u32* src = (const u32*)(knn_in + (size_t)((b << 12) | i0) * KNN);
        for (int k = tid; k < 16 * KNN / 2; k += 128) ((u32*)idx)[k] = src[k];
    }
    __syncthreads();

#pragma unroll
    for (int pp = 0; pp < 8; ++pp) {
        int p = w * 8 + pp;
        int i = i0 + p;
        float af = 0.f, al = 0.f;
        float hfv = ftb[(size_t)i * 64 + lane];
        float hlv = (lane < 3) ? pkb[(size_t)i * 4 + lane] : 0.f;
#pragma unroll
        for (int t = 0; t < KNN; ++t) {       // ascending (dist, idx) order
            int j = idx[p * KNN + t];
            af += ftb[(size_t)j * 64 + lane];
            if (lane < 3) al += pkb[(size_t)j * 4 + lane];
        }
        aggf[p][3 + lane] = af;
        hif[p][3 + lane]  = hfv;
        if (lane < 3) { aggf[p][lane] = al; hif[p][lane] = hlv; }
    }
    __syncthreads();

    const int p2 = tid & 15, oct = tid >> 4;  // 8 channels per thread
    const int i2 = i0 + p2;
    float rel[8], root[8];
#pragma unroll
    for (int c = 0; c < 8; ++c) { rel[c] = 0.f; root[c] = 0.f; }
    for (int f = 0; f < FIN; ++f) {
        float a = aggf[p2][f];
        float h = hif[p2][f];
        const float4* w4r = (const float4*)(Wrel + f * COUT + oct * 8);
        const float4* w4o = (const float4*)(Wroot + f * COUT + oct * 8);
#pragma unroll
        for (int c4 = 0; c4 < 2; ++c4) {
            float4 wr = w4r[c4], wo = w4o[c4];
            rel[c4 * 4 + 0] += a * wr.x;  root[c4 * 4 + 0] += h * wo.x;
            rel[c4 * 4 + 1] += a * wr.y;  root[c4 * 4 + 1] += h * wo.y;
            rel[c4 * 4 + 2] += a * wr.z;  root[c4 * 4 + 2] += h * wo.z;
            rel[c4 * 4 + 3] += a * wr.w;  root[c4 * 4 + 3] += h * wo.w;
        }
    }
    const size_t ob = (size_t)NB * 3 * N_PTS + (size_t)b * COUT * N_PTS;
#pragma unroll
    for (int c = 0; c < 8; ++c) {
        int cc = oct * 8 + c;
        float acc = (rel[c] + brel[cc]) + root[c];  // einsum + b_rel + einsum order
        out[ob + (size_t)cc * N_PTS + i2] = fmaxf(acc, 0.f);
    }
}

// ================= r14 fallback path (proven, 379us) =================
__global__ __launch_bounds__(256) void knn_seg8_kernel(
    const float* __restrict__ xloc, u16* __restrict__ knn_out) {
    __shared__ u64 stk[SLOTS][256];
    __shared__ u64 ext[KNN - SLOTS][256];
    const int tid  = threadIdx.x;
    const int q    = tid & 31;
    const int seg  = tid >> 5;
    const int blk  = blockIdx.x;
    const int b    = blk >> 7;
    const int i    = ((blk & 127) << 5) | q;
    const float* xb = xloc + (size_t)b * 3 * N_PTS;

    const float xi = xb[i], yi = xb[N_PTS + i], zi = xb[2 * N_PTS + i];
    const float sqi = sq_exact(xi, yi, zi);

    u64 ld[32];
#pragma unroll
    for (int t = 0; t < 32; ++t) ld[t] = ~0ull;
    u64 thr = ~0ull;
    int cnt = 0;

    auto merge_stack = [&]() {
        u64 bd[SLOTS];
#pragma unroll
        for (int t = 0; t < SLOTS; ++t) bd[t] = (t < cnt) ? stk[t][tid] : ~0ull;
#pragma unroll
        for (int k = 2; k <= SLOTS; k <<= 1) {
#pragma unroll
            for (int s = k >> 1; s > 0; s >>= 1) {
#pragma unroll
                for (int t = 0; t < SLOTS; ++t) {
                    int l = t ^ s;
                    if (l > t) {
                        if ((t & k) == 0) cswap64(bd[t], bd[l]);
                        else              cswap64(bd[l], bd[t]);
                    }
                }
            }
        }
#pragma unroll
        for (int t = 0; t < SLOTS; ++t) cswap64(ld[31 - t], bd[t]);
#pragma unroll
        for (int k = 16; k >= 1; k >>= 1) {
#pragma unroll
            for (int t = 0; t < 32; ++t) {
                if ((t & k) == 0) cswap64(ld[t], ld[t | k]);
            }
        }
        thr = ld[KNN - 1];
        cnt = 0;
    };

    const int cbase = seg * 512;
    for (int c = 0; c < 512; c += 4) {
        const int cc = cbase + c;
        float4 fx = *(const float4*)(xb + cc);
        float4 fy = *(const float4*)(xb + N_PTS + cc);
        float4 fz = *(const float4*)(xb + 2 * N_PTS + cc);
#pragma unroll
        for (int qq = 0; qq < 4; ++qq) {
            float xj = (qq == 0) ? fx.x : (qq == 1) ? fx.y : (qq == 2) ? fx.z : fx.w;
            float yj = (qq == 0) ? fy.x : (qq == 1) ? fy.y : (qq == 2) ? fy.z : fy.w;
            float zj = (qq == 0) ? fz.x : (qq == 1) ? fz.y : (qq == 2) ? fz.z : fz.w;
            float sqj = sq_exact(xj, yj, zj);
            float d = dist_from_sq(xi, yi, zi, sqi, xj, yj, zj, sqj);
            int j = cc + qq;
            u64 key = ((u64)fmap(d) << 12) | (u32)j;
            bool ok = (j != i) && (key < thr);
            if (ok) { stk[cnt][tid] = key; ++cnt; }
        }
        if (__any(cnt >= SLOTS - 3)) merge_stack();
    }
    merge_stack();

#pragma unroll
    for (int t = 0; t < SLOTS; ++t) stk[t][tid] = ld[t];
#pragma unroll
    for (int t = SLOTS; t < KNN; ++t) ext[t - SLOTS][tid] = ld[t];
    __syncthreads();

    if (tid < 32) {
        const int col0 = tid;
        const int row  = (b << 12) | ((blk & 127) << 5) | tid;
        int  pp[8];
        u64  kk[8];
#pragma unroll
        for (int s = 0; s < 8; ++s) { pp[s] = 0; kk[s] = stk[0][col0 + 32 * s]; }
#pragma unroll
        for (int t = 0; t < KNN; ++t) {
            u64 best = kk[0]; int sm = 0;
#pragma unroll
            for (int s = 1; s < 8; ++s)
                if (kk[s] < best) { best = kk[s]; sm = s; }
            knn_out[(size_t)row * KNN + t] = (u16)(best & 0xFFFu);
#pragma unroll
            for (int s = 0; s < 8; ++s) {
                if (s == sm) {
                    int p = ++pp[s];
                    int col = col0 + 32 * s;
                    kk[s] = (p < KNN) ? ((p < SLOTS) ? stk[p][col] : ext[p - SLOTS][col])
                                      : ~0ull;
                }
            }
        }
    }
}

__global__ __launch_bounds__(128) void conv_q_kernel(
    const float* __restrict__ xloc,
    const float* __restrict__ xfeat,
    const float* __restrict__ Wrel,
    const float* __restrict__ brel,
    const float* __restrict__ Wroot,
    const u16* __restrict__ knn_in,
    float* __restrict__ out) {
    __shared__ float rowbuf[2][N_PTS];
    const int tid = threadIdx.x;
    const int p   = tid & 31;
    const int qtr = tid >> 5;
    const int blk = blockIdx.x;
    const int b   = blk >> 7;
    const int i   = ((blk & 127) << 5) | p;
    const float* xb = xloc + (size_t)b * 3 * N_PTS;
    const float* fb = xfeat + (size_t)b * 64 * N_PTS;

    if (qtr == 0) {
#pragma unroll
        for (int c = 0; c < 3; ++c)
            out[((size_t)b * 3 + c) * N_PTS + i] = xb[(size_t)c * N_PTS + i];
    }

    u32 kl[KNN / 2];
    const u32* kp = (const u32*)(knn_in + (size_t)((b << 12) | i) * KNN);
#pragma unroll
    for (int w = 0; w < KNN / 2; ++w) kl[w] = kp[w];
    int jj[KNN];
#pragma unroll
    for (int t = 0; t < KNN; ++t) jj[t] = (int)((kl[t >> 1] >> ((t & 1) * 16)) & 0xFFFFu);

    float rel[16], root[16];
#pragma unroll
    for (int c = 0; c < 16; ++c) { rel[c] = 0.f; root[c] = 0.f; }

    auto stage = [&](int f) {
        const float* src = (f < 3) ? (xb + (size_t)f * N_PTS)
                                   : (fb + (size_t)(f - 3) * N_PTS);
        const float4* s4 = (const float4*)src;
        float4* d4 = (float4*)rowbuf[f & 1];
#pragma unroll
        for (int w = 0; w < 8; ++w) {
            int idxw = w * 128 + tid;
            d4[idxw] = s4[idxw];
        }
    };

    stage(0);
    __syncthreads();

    for (int f = 0; f < FIN; ++f) {
        if (f + 1 < FIN) stage(f + 1);
        const float* cur = rowbuf[f & 1];
        float hf = cur[i];
        float af = 0.f;
#pragma unroll
        for (int t = 0; t < KNN; ++t) af += cur[jj[t]];

        const float4* w4r = (const float4*)(Wrel + f * COUT + qtr * 16);
        const float4* w4o = (const float4*)(Wroot + f * COUT + qtr * 16);
#pragma unroll
        for (int c4 = 0; c4 < 4; ++c4) {
            float4 wr = w4r[c4], wo = w4o[c4];
            rel[c4 * 4 + 0] += af * wr.x;  root[c4 * 4 + 0] += hf * wo.x;
            rel[c4 * 4 + 1] += af * wr.y;  root[c4 * 4 + 1] += hf * wo.y;
            rel[c4 * 4 + 2] += af * wr.z;  root[c4 * 4 + 2] += hf * wo.z;
            rel[c4 * 4 + 3] += af * wr.w;  root[c4 * 4 + 3] += hf * wo.w;
        }
        __syncthreads();
    }

    const size_t ob = (size_t)NB * 3 * N_PTS + (size_t)b * COUT * N_PTS;
#pragma unroll
    for (int c = 0; c < 16; ++c) {
        int cc = qtr * 16 + c;
        float acc = (rel[c] + brel[cc]) + root[c];
        out[ob + (size_t)cc * N_PTS + i] = fmaxf(acc, 0.f);
    }
}

// ---------------- Last-resort fallback: proven round-7 monolith ----------------
__device__ __forceinline__ void insert3(float d, int c,
                                        float& v0, float& v1, float& v2,
                                        int& c0, int& c1, int& c2) {
    if (d < v2) {
        if (d < v1) {
            if (d < v0) { v2 = v1; c2 = c1; v1 = v0; c1 = c0; v0 = d; c0 = c; }
            else        { v2 = v1; c2 = c1; v1 = d;  c1 = c; }
        } else          { v2 = d;  c2 = c; }
    }
}

__global__ __launch_bounds__(64) void pcd_all(
    const float* __restrict__ xloc,
    const float* __restrict__ xfeat,
    const float* __restrict__ Wrel,
    const float* __restrict__ brel,
    const float* __restrict__ Wroot,
    float* __restrict__ out) {
    const int lane = threadIdx.x;
    const int row  = blockIdx.x;
    const int b    = row >> 12;
    const int i    = row & (N_PTS - 1);
    const float* xb = xloc + (size_t)b * 3 * N_PTS;

    if (lane < 3) {
        out[((size_t)b * 3 + lane) * N_PTS + i] = xb[(size_t)lane * N_PTS + i];
    }

    const float xi  = xb[i];
    const float yi  = xb[N_PTS + i];
    const float zi  = xb[2 * N_PTS + i];
    const float sqi = sq_exact(xi, yi, zi);

    float v0 = 1e30f, v1 = 1e30f, v2 = 1e30f;
    int   c0 = -1,    c1 = -1,    c2 = -1;

    for (int s = 0; s < 16; ++s) {
        int jb = s * 256 + lane * 4;
        float4 fx = *(const float4*)(xb + jb);
        float4 fy = *(const float4*)(xb + N_PTS + jb);
        float4 fz = *(const float4*)(xb + 2 * N_PTS + jb);
#pragma unroll
        for (int q = 0; q < 4; ++q) {
            float xj = (q == 0) ? fx.x : (q == 1) ? fx.y : (q == 2) ? fx.z : fx.w;
            float yj = (q == 0) ? fy.x : (q == 1) ? fy.y : (q == 2) ? fy.z : fy.w;
            float zj = (q == 0) ? fz.x : (q == 1) ? fz.y : (q == 2) ? fz.z : fz.w;
            int j = jb + q;
            float d = (j == i) ? 1e30f : dist_exact(xi, yi, zi, sqi, xj, yj, zj);
            insert3(d, s * 4 + q, v0, v1, v2, c0, c1, c2);
        }
    }

    u64 taken = 0;
    __shared__ int knn[KNN];

    for (int t = 0; t < KNN; ++t) {
        float bv = v0;
        int   bj = (c0 >= 0) ? (((c0 >> 2) << 8) + lane * 4 + (c0 & 3)) : (N_PTS - 1);
#pragma unroll
        for (int m = 1; m < 64; m <<= 1) {
            float ov = __shfl_xor(bv, m);
            int   oj = __shfl_xor(bj, m);
            if (ov < bv || (ov == bv && oj < bj)) { bv = ov; bj = oj; }
        }
        if (lane == 0) knn[t] = bj & (N_PTS - 1);
        int owner = (bj >> 2) & 63;
        if (lane == owner) {
            int cw = (((bj >> 8) << 2) | (bj & 3)) & 63;
            taken |= (1ull << cw);
            v0 = v1; c0 = c1; v1 = v2; c1 = c2; v2 = 1e30f; c2 = -1;
            if (v0 >= 1e30f) {
                v0 = v1 = v2 = 1e30f; c0 = c1 = c2 = -1;
                for (int s = 0; s < 16; ++s) {
                    int jb = s * 256 + lane * 4;
                    float4 fx = *(const float4*)(xb + jb);
                    float4 fy = *(const float4*)(xb + N_PTS + jb);
                    float4 fz = *(const float4*)(xb + 2 * N_PTS + jb);
#pragma unroll
                    for (int q = 0; q < 4; ++q) {
                        int cc = s * 4 + q;
                        if ((taken >> cc) & 1ull) continue;
                        int j = jb + q;
                        if (j == i) continue;
                        float xj = (q == 0) ? fx.x : (q == 1) ? fx.y : (q == 2) ? fx.z : fx.w;
                        float yj = (q == 0) ? fy.x : (q == 1) ? fy.y : (q == 2) ? fy.z : fy.w;
                        float zj = (q == 0) ? fz.x : (q == 1) ? fz.y : (q == 2) ? fz.z : fz.w;
                        float d = dist_exact(xi, yi, zi, sqi, xj, yj, zj);
                        insert3(d, cc, v0, v1, v2, c0, c1, c2);
                    }
                }
            }
        }
    }

    __syncthreads();

    __shared__ float aggf[FIN + 1];
    __shared__ float hif[FIN + 1];

    const float* xfb = xfeat + ((size_t)b * 64 + lane) * N_PTS;
    const float* xlb = xb + (size_t)(lane < 3 ? lane : 0) * N_PTS;
    float af = 0.f, al = 0.f;
    for (int t = 0; t < KNN; ++t) {
        int j = knn[t];
        af += xfb[j];
        if (lane < 3) al += xlb[j];
    }
    aggf[3 + lane] = af;
    hif[3 + lane]  = xfb[i];
    if (lane < 3) { aggf[lane] = al; hif[lane] = xlb[i]; }
    __syncthreads();

    float acc_rel = 0.f, acc_root = 0.f;
    for (int f = 0; f < FIN; ++f) {
        acc_rel  += aggf[f] * Wrel[f * COUT + lane];
        acc_root += hif[f]  * Wroot[f * COUT + lane];
    }
    float acc = (acc_rel + brel[lane]) + acc_root;
    acc = fmaxf(acc, 0.0f);
    out[(size_t)NB * 3 * N_PTS + ((((size_t)b << 6) | lane) << 12) + i] = acc;
}

extern "C" void kernel_launch(void* const* d_in, const int* in_sizes, int n_in,
                              void* d_out, int out_size, void* d_ws, size_t ws_size,
                              hipStream_t stream) {
    const float* xloc  = nullptr;
    const float* xfeat = nullptr;
    const float* Wrel  = nullptr;
    const float* brel  = nullptr;
    const float* Wroot = nullptr;
    for (int idx = 0; idx < n_in; ++idx) {
        const long long s = in_sizes[idx];
        const float* p = (const float*)d_in[idx];
        if (s == 98304LL || s == 393216LL)          { xloc = p; }
        else if (s == 2097152LL || s == 8388608LL)  { xfeat = p; }
        else if (s == 4288LL || s == 17152LL)       { if (!Wrel) Wrel = p; else Wroot = p; }
        else if (s == 64LL || s == 256LL)           { brel = p; }
    }
    if (!xloc || !xfeat || !Wrel || !brel || !Wroot) {
        xloc  = (const float*)d_in[0];
        xfeat = (const float*)d_in[1];
        Wrel  = (const float*)d_in[2];
        brel  = (const float*)d_in[3];
        Wroot = (const float*)d_in[4];
    }

    if (d_ws != nullptr && ws_size >= (size_t)WS_NEED) {
        u16*    knn_ws = (u16*)d_ws;
        float*  ft     = (float*)((char*)d_ws + FT_OFF);
        float4* pack   = (float4*)((char*)d_ws + PK_OFF);
        transpose_kernel<<<dim3(NB * 64), dim3(256), 0, stream>>>(
            xloc, xfeat, ft, pack, (float*)d_out);
        knn_v6_kernel<<<dim3(NB * 64), dim3(BT), 0, stream>>>(pack, knn_ws);
        conv_g2_kernel<<<dim3(NB * 256), dim3(128), 0, stream>>>(
            Wrel, brel, Wroot, knn_ws, ft, pack, (float*)d_out);
    } else if (d_ws != nullptr && ws_size >= (size_t)KNN_BYTES) {
        u16* knn_ws = (u16*)d_ws;
        knn_seg8_kernel<<<dim3(NB * 128), dim3(256), 0, stream>>>(xloc, knn_ws);
        conv_q_kernel<<<dim3(NB * 128), dim3(128), 0, stream>>>(
            xloc, xfeat, Wrel, brel, Wroot, knn_ws, (float*)d_out);
    } else {
        pcd_all<<<dim3(NB * N_PTS), dim3(64), 0, stream>>>(
            xloc, xfeat, Wrel, brel, Wroot, (float*)d_out);
    }
}